// Round 1
// baseline (30239.041 us; speedup 1.0000x reference)
//
#include <hip/hip_runtime.h>

#define SEQ    1000
#define BATCH  256
#define HID    256
#define NL     10
#define G4H    1024                    // 4*HID
#define WELT   (NL * G4H * HID)        // 2,621,440 elements per weight tensor
#define BH     (BATCH * HID)           // 65,536
#define NBLK   160
#define NSTEPS (SEQ + NL - 1)

typedef __bf16 bf16x8 __attribute__((ext_vector_type(8)));
typedef float  f32x4  __attribute__((ext_vector_type(4)));

// ---- ws layout (bytes) ----
// 0          : wih_bf   (5,242,880)
// 5,242,880  : whh_bf   (5,242,880)
// 10,485,760 : biasc    (40,960)      fp32, b_ih+b_hh combined
// 10,526,720 : scb      (2,621,440)   bf16 h-state, [NL][2(parity)][B][H]
// 13,148,160 : cbuf     (2,359,296)   bf16 layer handoff, [NL-1][2(parity)][B][H]
// 15,507,456 : bar      (8)           grid barrier {count, generation}

// -------- prologue: bf16 weights, combined bias, zeroed state, zeroed barrier --------
__global__ __launch_bounds__(256) void lstm_prep(
    const float* __restrict__ Wih, const float* __restrict__ Whh,
    const float* __restrict__ bih, const float* __restrict__ bhh,
    __bf16* __restrict__ wih_bf, __bf16* __restrict__ whh_bf,
    float* __restrict__ biasc, __bf16* __restrict__ scb,
    unsigned int* __restrict__ bar)
{
    const int i0 = blockIdx.x * blockDim.x + threadIdx.x;
    const int stride = gridDim.x * blockDim.x;
    for (int i = i0; i < WELT; i += stride) {
        wih_bf[i] = (__bf16)Wih[i];
        whh_bf[i] = (__bf16)Whh[i];
    }
    for (int i = i0; i < NL * G4H; i += stride) biasc[i] = bih[i] + bhh[i];
    for (int i = i0; i < NL * 2 * BH; i += stride) scb[i] = (__bf16)0.0f;
    if (i0 == 0) { bar[0] = 0u; bar[1] = 0u; }
}

// -------- device-scope grid barrier (all NBLK blocks co-resident by construction) --------
__device__ __forceinline__ void grid_barrier(unsigned int* __restrict__ bar)
{
    __syncthreads();
    if (threadIdx.x == 0) {
        unsigned int* cnt = bar;
        unsigned int* gen = bar + 1;
        const unsigned int g =
            __hip_atomic_load(gen, __ATOMIC_RELAXED, __HIP_MEMORY_SCOPE_AGENT);
        const unsigned int a =
            __hip_atomic_fetch_add(cnt, 1u, __ATOMIC_ACQ_REL, __HIP_MEMORY_SCOPE_AGENT);
        if (a == NBLK - 1) {
            __hip_atomic_store(cnt, 0u, __ATOMIC_RELAXED, __HIP_MEMORY_SCOPE_AGENT);
            __hip_atomic_store(gen, g + 1u, __ATOMIC_RELEASE, __HIP_MEMORY_SCOPE_AGENT);
        } else {
            unsigned int cg;
            do {
                __builtin_amdgcn_s_sleep(1);
                cg = __hip_atomic_load(gen, __ATOMIC_RELAXED, __HIP_MEMORY_SCOPE_AGENT);
            } while (cg == g);
            (void)__hip_atomic_load(gen, __ATOMIC_ACQUIRE, __HIP_MEMORY_SCOPE_AGENT);
        }
    }
    __syncthreads();
}

// -------- main persistent wavefront kernel --------
// block -> (layer j = blk>>4, tile = blk&15): b0 = (tile>>2)*64, h0 = (tile&3)*64
// wave v (0..3) owns h columns h0+v*16 .. +16, all 64 batch rows of the tile.
__global__ __launch_bounds__(256, 1) void lstm_main(
    const float* __restrict__ x,
    const __bf16* __restrict__ wih_bf, const __bf16* __restrict__ whh_bf,
    const float* __restrict__ biasc,
    __bf16* __restrict__ scb, __bf16* __restrict__ cbuf,
    float* __restrict__ out, unsigned int* __restrict__ bar)
{
    __shared__ __bf16 Alds[64][512];   // exactly 64 KiB; XOR-swizzled 8-elt chunks

    const int blk  = blockIdx.x;
    const int j    = blk >> 4;
    const int tile = blk & 15;
    const int b0   = (tile >> 2) << 6;
    const int h0   = (tile & 3)  << 6;
    const int tid  = threadIdx.x;
    const int v    = tid >> 6;
    const int lane = tid & 63;
    const int m    = lane & 15;        // MFMA A-row / B-col / D-col index
    const int q    = lane >> 4;        // quad
    const int hw   = h0 + v * 16 + m;  // this lane's h column (N index)

    // per-gate weight row pointers (W is [N=4H][K=H] = B^T layout; 8 k's per lane)
    const __bf16* bihp[4];
    const __bf16* bhhp[4];
    float biasg[4];
#pragma unroll
    for (int g = 0; g < 4; ++g) {
        const size_t row = (size_t)j * G4H + g * HID + hw;
        bihp[g] = wih_bf + row * HID + q * 8;
        bhhp[g] = whh_bf + row * HID + q * 8;
        biasg[g] = biasc[(size_t)j * G4H + g * HID + hw];
    }

    float c_state[4][4];               // fp32 cell state, fixed ownership -> registers
#pragma unroll
    for (int bs = 0; bs < 4; ++bs)
#pragma unroll
        for (int r = 0; r < 4; ++r) c_state[bs][r] = 0.0f;

    for (int s = 0; s < NSTEPS; ++s) {
        const int t = s - j;
        if (t >= 0 && t < SEQ) {
            const int par = t & 1;
            const __bf16* hprev = scb + (size_t)(j * 2 + ((t + 1) & 1)) * BH;
            __bf16* hout = scb + (size_t)(j * 2 + par) * BH;

            __syncthreads();  // protect Alds from previous step's readers
            // ---- stage A = [cur(k<256) | h_prev(k>=256)] rows b0..b0+63 into LDS ----
            if (j == 0) {
                const float* xt = x + (size_t)t * BH;
#pragma unroll
                for (int i = 0; i < 16; ++i) {
                    const int row = i * 4 + v;
                    const int cp  = lane ^ (row & 7);
                    const int k   = lane * 8;
                    __bf16* dst = &Alds[row][cp * 8];
                    if (k < HID) {
                        const float4* p = (const float4*)(xt + (size_t)(b0 + row) * HID + k);
                        const float4 u0 = p[0];
                        const float4 u1 = p[1];
                        bf16x8 vv;
                        vv[0] = (__bf16)u0.x; vv[1] = (__bf16)u0.y;
                        vv[2] = (__bf16)u0.z; vv[3] = (__bf16)u0.w;
                        vv[4] = (__bf16)u1.x; vv[5] = (__bf16)u1.y;
                        vv[6] = (__bf16)u1.z; vv[7] = (__bf16)u1.w;
                        *(bf16x8*)dst = vv;
                    } else {
                        *(bf16x8*)dst =
                            *(const bf16x8*)(hprev + (size_t)(b0 + row) * HID + (k - HID));
                    }
                }
            } else {
                const __bf16* ct = cbuf + (size_t)((j - 1) * 2 + par) * BH;
#pragma unroll
                for (int i = 0; i < 16; ++i) {
                    const int row = i * 4 + v;
                    const int cp  = lane ^ (row & 7);
                    const int k   = lane * 8;
                    const __bf16* src = (k < HID)
                        ? (ct + (size_t)(b0 + row) * HID + k)
                        : (hprev + (size_t)(b0 + row) * HID + (k - HID));
                    *(bf16x8*)&Alds[row][cp * 8] = *(const bf16x8*)src;
                }
            }
            __syncthreads();

            // ---- K loop: gates = cur@Wih^T + h_prev@Whh^T + bias ----
            f32x4 acc[4][4];   // [b-subtile][gate]
#pragma unroll
            for (int g = 0; g < 4; ++g) {
                const float bb = biasg[g];
                const f32x4 bv = {bb, bb, bb, bb};
#pragma unroll
                for (int bs = 0; bs < 4; ++bs) acc[bs][g] = bv;
            }
#pragma unroll
            for (int ch = 0; ch < 8; ++ch) {
                bf16x8 bfr[4];
#pragma unroll
                for (int g = 0; g < 4; ++g)
                    bfr[g] = *(const bf16x8*)(bihp[g] + ch * 32);
#pragma unroll
                for (int bs = 0; bs < 4; ++bs) {
                    const int rowA = bs * 16 + m;
                    const int cp = (ch * 4 + q) ^ (rowA & 7);
                    const bf16x8 af = *(const bf16x8*)&Alds[rowA][cp * 8];
#pragma unroll
                    for (int g = 0; g < 4; ++g)
                        acc[bs][g] = __builtin_amdgcn_mfma_f32_16x16x32_bf16(
                            af, bfr[g], acc[bs][g], 0, 0, 0);
                }
            }
#pragma unroll
            for (int ch = 0; ch < 8; ++ch) {
                bf16x8 bfr[4];
#pragma unroll
                for (int g = 0; g < 4; ++g)
                    bfr[g] = *(const bf16x8*)(bhhp[g] + ch * 32);
#pragma unroll
                for (int bs = 0; bs < 4; ++bs) {
                    const int rowA = bs * 16 + m;
                    const int cp = (32 + ch * 4 + q) ^ (rowA & 7);
                    const bf16x8 af = *(const bf16x8*)&Alds[rowA][cp * 8];
#pragma unroll
                    for (int g = 0; g < 4; ++g)
                        acc[bs][g] = __builtin_amdgcn_mfma_f32_16x16x32_bf16(
                            af, bfr[g], acc[bs][g], 0, 0, 0);
                }
            }

            // ---- epilogue: gate activations, state update, handoff ----
            // D mapping: col = lane&15 (= h), row = q*4 + r (= batch within subtile)
            __bf16* cnext = (j < NL - 1) ? (cbuf + (size_t)(j * 2 + par) * BH) : (__bf16*)0;
#pragma unroll
            for (int bs = 0; bs < 4; ++bs) {
#pragma unroll
                for (int r = 0; r < 4; ++r) {
                    const int b = b0 + bs * 16 + q * 4 + r;
                    const float gi = acc[bs][0][r];
                    const float gf = acc[bs][1][r];
                    const float gg = acc[bs][2][r];
                    const float go = acc[bs][3][r];
                    const float ii = 1.0f / (1.0f + __expf(-gi));
                    const float ff = 1.0f / (1.0f + __expf(-gf));
                    const float tg = 1.0f - 2.0f / (__expf(2.0f * gg) + 1.0f);
                    const float oo = 1.0f / (1.0f + __expf(-go));
                    const float cn = ff * c_state[bs][r] + ii * tg;     // c' (ref: sh_new, next cur)
                    const float tc = 1.0f - 2.0f / (__expf(2.0f * cn) + 1.0f);
                    const float hn = oo * tc;                            // h' (ref: sc_new)
                    c_state[bs][r] = cn;
                    hout[(size_t)b * HID + hw] = (__bf16)hn;
                    if (j < NL - 1) {
                        cnext[(size_t)b * HID + hw] = (__bf16)cn;
                    } else if (t == SEQ - 1) {
                        out[(size_t)b * HID + hw] = cn;                  // fp32, unquantized
                    }
                }
            }
        }
        grid_barrier(bar);
    }
}

extern "C" void kernel_launch(void* const* d_in, const int* in_sizes, int n_in,
                              void* d_out, int out_size, void* d_ws, size_t ws_size,
                              hipStream_t stream)
{
    (void)in_sizes; (void)n_in; (void)out_size; (void)ws_size;
    const float* x   = (const float*)d_in[0];
    const float* Wih = (const float*)d_in[1];
    const float* Whh = (const float*)d_in[2];
    const float* bih = (const float*)d_in[3];
    const float* bhh = (const float*)d_in[4];
    float* out = (float*)d_out;

    char* ws = (char*)d_ws;
    __bf16* wih_bf = (__bf16*)(ws);
    __bf16* whh_bf = (__bf16*)(ws + 5242880);
    float*  biasc  = (float*) (ws + 10485760);
    __bf16* scb    = (__bf16*)(ws + 10526720);
    __bf16* cbuf   = (__bf16*)(ws + 13148160);
    unsigned int* bar = (unsigned int*)(ws + 15507456);

    lstm_prep<<<dim3(1024), dim3(256), 0, stream>>>(
        Wih, Whh, bih, bhh, wih_bf, whh_bf, biasc, scb, bar);
    lstm_main<<<dim3(NBLK), dim3(256), 0, stream>>>(
        x, wih_bf, whh_bf, biasc, scb, cbuf, out, bar);
}

// Round 2
// 19524.117 us; speedup vs baseline: 1.5488x; 1.5488x over previous
//
#include <hip/hip_runtime.h>

#define SEQ    1000
#define BATCH  256
#define HID    256
#define NL     10
#define G4H    1024                    // 4*HID
#define WELT   (NL * G4H * HID)        // 2,621,440 elements per weight tensor
#define BH     (BATCH * HID)           // 65,536
#define NBLK   160

typedef __bf16 bf16x8 __attribute__((ext_vector_type(8)));
typedef float  f32x4  __attribute__((ext_vector_type(4)));

// ---- ws layout (bytes) ----
// 0          : wih_bf   (5,242,880)
// 5,242,880  : whh_bf   (5,242,880)
// 10,485,760 : biasc    (40,960)      fp32, b_ih+b_hh combined
// 10,526,720 : scb      (2,621,440)   bf16 h-state, [NL][2(parity)][B][H]
// 13,148,160 : cbuf     (2,359,296)   bf16 layer handoff, [NL-1][2(parity)][B][H]
// 15,507,456 : done     (640)         per-layer step counters, stride 16 uints (64 B)

// -------- prologue --------
__global__ __launch_bounds__(256) void lstm_prep(
    const float* __restrict__ Wih, const float* __restrict__ Whh,
    const float* __restrict__ bih, const float* __restrict__ bhh,
    __bf16* __restrict__ wih_bf, __bf16* __restrict__ whh_bf,
    float* __restrict__ biasc, __bf16* __restrict__ scb,
    unsigned int* __restrict__ done)
{
    const int i0 = blockIdx.x * blockDim.x + threadIdx.x;
    const int stride = gridDim.x * blockDim.x;
    for (int i = i0; i < WELT; i += stride) {
        wih_bf[i] = (__bf16)Wih[i];
        whh_bf[i] = (__bf16)Whh[i];
    }
    for (int i = i0; i < NL * G4H; i += stride) biasc[i] = bih[i] + bhh[i];
    for (int i = i0; i < NL * 2 * BH; i += stride) scb[i] = (__bf16)0.0f;
    if (i0 < NL * 16) done[i0] = 0u;
}

// -------- spin until *p >= tgt (relaxed poll, acquire confirm) --------
__device__ __forceinline__ void spin_ge(unsigned int* p, unsigned int tgt)
{
    for (;;) {
        const unsigned int v =
            __hip_atomic_load(p, __ATOMIC_RELAXED, __HIP_MEMORY_SCOPE_AGENT);
        if (v >= tgt) break;
        __builtin_amdgcn_s_sleep(1);
    }
    (void)__hip_atomic_load(p, __ATOMIC_ACQUIRE, __HIP_MEMORY_SCOPE_AGENT);
}

// -------- main persistent kernel, per-layer flag sync --------
// XCD-aware swizzle (assumes blk -> XCD blk%8; perf-only heuristic):
//   blk < 128 : layer j = blk&7  (whole layer on XCD j), tile = blk>>3
//   blk >=128 : layer j = 8 + ((blk&7)>>2), h-tile = blk&3, b-tile = (blk-128)>>3
// tile: b0 = (tile>>2)*64, h0 = (tile&3)*64. Wave v owns h cols h0+v*16..+16.
__global__ __launch_bounds__(256, 1) void lstm_main(
    const float* __restrict__ x,
    const __bf16* __restrict__ wih_bf, const __bf16* __restrict__ whh_bf,
    const float* __restrict__ biasc,
    __bf16* __restrict__ scb, __bf16* __restrict__ cbuf,
    float* __restrict__ out, unsigned int* __restrict__ done)
{
    __shared__ __bf16 Alds[64][512];   // 64 KiB; 16B-chunk XOR swizzle

    const int blk  = blockIdx.x;
    int j, tile;
    if (blk < 128) { j = blk & 7; tile = blk >> 3; }
    else           { j = 8 + ((blk & 7) >> 2); tile = (((blk - 128) >> 3) << 2) | (blk & 3); }
    const int b0   = (tile >> 2) << 6;
    const int h0   = (tile & 3)  << 6;
    const int tid  = threadIdx.x;
    const int v    = tid >> 6;
    const int lane = tid & 63;
    const int m    = lane & 15;        // MFMA A-row / B-col / D-col index
    const int q    = lane >> 4;        // quad
    const int hw   = h0 + v * 16 + m;  // this lane's h column (N index)

    unsigned int* done_self = done + j * 16;
    unsigned int* done_prod = done + (j - 1) * 16;
    unsigned int* done_cons = done + (j + 1) * 16;

    const __bf16* bihp[4];
    const __bf16* bhhp[4];
    float biasg[4];
#pragma unroll
    for (int g = 0; g < 4; ++g) {
        const size_t row = (size_t)j * G4H + g * HID + hw;
        bihp[g] = wih_bf + row * HID + q * 8;
        bhhp[g] = whh_bf + row * HID + q * 8;
        biasg[g] = biasc[(size_t)j * G4H + g * HID + hw];
    }

    float c_state[4][4];
#pragma unroll
    for (int bs = 0; bs < 4; ++bs)
#pragma unroll
        for (int r = 0; r < 4; ++r) c_state[bs][r] = 0.0f;

    for (int t = 0; t < SEQ; ++t) {
        const int par = t & 1;
        const __bf16* hprev = scb + (size_t)(j * 2 + ((t + 1) & 1)) * BH;
        __bf16* hout = scb + (size_t)(j * 2 + par) * BH;

        // ---- W2: own layer finished step t-1 (h ready, hout slot reusable) ----
        if (tid == 0 && t >= 1) spin_ge(done_self, 16u * (unsigned)t);
        __syncthreads();

        // ---- stage h_prev into Alds hi half (chunks 32..63) ----
#pragma unroll
        for (int i = 0; i < 8; ++i) {
            const int row = i * 8 + v * 2 + (lane >> 5);
            const int c32 = lane & 31;
            const int cp  = (32 + c32) ^ (row & 7);
            *(bf16x8*)&Alds[0][0 + (size_t)row * 512 + cp * 8] =
                *(const bf16x8*)(hprev + (size_t)(b0 + row) * HID + c32 * 8);
        }
        __syncthreads();

        // ---- acc = bias; Whh @ h_prev (hi chunks) ----
        f32x4 acc[4][4];   // [b-subtile][gate]
#pragma unroll
        for (int g = 0; g < 4; ++g) {
            const float bb = biasg[g];
            const f32x4 bv = {bb, bb, bb, bb};
#pragma unroll
            for (int bs = 0; bs < 4; ++bs) acc[bs][g] = bv;
        }
#pragma unroll
        for (int ch = 0; ch < 8; ++ch) {
            bf16x8 bfr[4];
#pragma unroll
            for (int g = 0; g < 4; ++g)
                bfr[g] = *(const bf16x8*)(bhhp[g] + ch * 32);
#pragma unroll
            for (int bs = 0; bs < 4; ++bs) {
                const int rowA = bs * 16 + m;
                const int cp = (32 + ch * 4 + q) ^ (rowA & 7);
                const bf16x8 af = *(const bf16x8*)&Alds[rowA][cp * 8];
#pragma unroll
                for (int g = 0; g < 4; ++g)
                    acc[bs][g] = __builtin_amdgcn_mfma_f32_16x16x32_bf16(
                        af, bfr[g], acc[bs][g], 0, 0, 0);
            }
        }

        // ---- W1: producer finished step t; W3: consumer finished t-2 ----
        if (tid == 0) {
            if (j > 0) spin_ge(done_prod, 16u * (unsigned)(t + 1));
            if (j < NL - 1 && t >= 2) spin_ge(done_cons, 16u * (unsigned)(t - 1));
        }
        __syncthreads();

        // ---- stage cur into Alds lo half (chunks 0..31) ----
        if (j == 0) {
            const float* xt = x + (size_t)t * BH;
#pragma unroll
            for (int i = 0; i < 8; ++i) {
                const int row = i * 8 + v * 2 + (lane >> 5);
                const int c32 = lane & 31;
                const int cp  = c32 ^ (row & 7);
                const float4* p = (const float4*)(xt + (size_t)(b0 + row) * HID + c32 * 8);
                const float4 u0 = p[0];
                const float4 u1 = p[1];
                bf16x8 vv;
                vv[0] = (__bf16)u0.x; vv[1] = (__bf16)u0.y;
                vv[2] = (__bf16)u0.z; vv[3] = (__bf16)u0.w;
                vv[4] = (__bf16)u1.x; vv[5] = (__bf16)u1.y;
                vv[6] = (__bf16)u1.z; vv[7] = (__bf16)u1.w;
                *(bf16x8*)&Alds[0][(size_t)row * 512 + cp * 8] = vv;
            }
        } else {
            const __bf16* ct = cbuf + (size_t)((j - 1) * 2 + par) * BH;
#pragma unroll
            for (int i = 0; i < 8; ++i) {
                const int row = i * 8 + v * 2 + (lane >> 5);
                const int c32 = lane & 31;
                const int cp  = c32 ^ (row & 7);
                *(bf16x8*)&Alds[0][(size_t)row * 512 + cp * 8] =
                    *(const bf16x8*)(ct + (size_t)(b0 + row) * HID + c32 * 8);
            }
        }
        __syncthreads();

        // ---- Wih @ cur (lo chunks) ----
#pragma unroll
        for (int ch = 0; ch < 8; ++ch) {
            bf16x8 bfr[4];
#pragma unroll
            for (int g = 0; g < 4; ++g)
                bfr[g] = *(const bf16x8*)(bihp[g] + ch * 32);
#pragma unroll
            for (int bs = 0; bs < 4; ++bs) {
                const int rowA = bs * 16 + m;
                const int cp = (ch * 4 + q) ^ (rowA & 7);
                const bf16x8 af = *(const bf16x8*)&Alds[rowA][cp * 8];
#pragma unroll
                for (int g = 0; g < 4; ++g)
                    acc[bs][g] = __builtin_amdgcn_mfma_f32_16x16x32_bf16(
                        af, bfr[g], acc[bs][g], 0, 0, 0);
            }
        }

        // ---- epilogue: activations, state update, publish ----
        __bf16* cnext = (j < NL - 1) ? (cbuf + (size_t)(j * 2 + par) * BH) : (__bf16*)0;
#pragma unroll
        for (int bs = 0; bs < 4; ++bs) {
#pragma unroll
            for (int r = 0; r < 4; ++r) {
                const int b = b0 + bs * 16 + q * 4 + r;
                const float gi = acc[bs][0][r];
                const float gf = acc[bs][1][r];
                const float gg = acc[bs][2][r];
                const float go = acc[bs][3][r];
                const float ii = 1.0f / (1.0f + __expf(-gi));
                const float ff = 1.0f / (1.0f + __expf(-gf));
                const float tg = 1.0f - 2.0f / (__expf(2.0f * gg) + 1.0f);
                const float oo = 1.0f / (1.0f + __expf(-go));
                const float cn = ff * c_state[bs][r] + ii * tg;   // c' (next layer's input)
                const float tc = 1.0f - 2.0f / (__expf(2.0f * cn) + 1.0f);
                const float hn = oo * tc;                          // h' (recurrent operand)
                c_state[bs][r] = cn;
                hout[(size_t)b * HID + hw] = (__bf16)hn;
                if (j < NL - 1) {
                    cnext[(size_t)b * HID + hw] = (__bf16)cn;
                } else if (t == SEQ - 1) {
                    out[(size_t)b * HID + hw] = cn;                // fp32, unquantized
                }
            }
        }

        __syncthreads();   // all threads' publishes issued (s_barrier drains vmcnt)
        if (tid == 0)
            __hip_atomic_fetch_add(done_self, 1u, __ATOMIC_RELEASE,
                                   __HIP_MEMORY_SCOPE_AGENT);
    }
}

extern "C" void kernel_launch(void* const* d_in, const int* in_sizes, int n_in,
                              void* d_out, int out_size, void* d_ws, size_t ws_size,
                              hipStream_t stream)
{
    (void)in_sizes; (void)n_in; (void)out_size; (void)ws_size;
    const float* x   = (const float*)d_in[0];
    const float* Wih = (const float*)d_in[1];
    const float* Whh = (const float*)d_in[2];
    const float* bih = (const float*)d_in[3];
    const float* bhh = (const float*)d_in[4];
    float* out = (float*)d_out;

    char* ws = (char*)d_ws;
    __bf16* wih_bf = (__bf16*)(ws);
    __bf16* whh_bf = (__bf16*)(ws + 5242880);
    float*  biasc  = (float*) (ws + 10485760);
    __bf16* scb    = (__bf16*)(ws + 10526720);
    __bf16* cbuf   = (__bf16*)(ws + 13148160);
    unsigned int* done = (unsigned int*)(ws + 15507456);

    lstm_prep<<<dim3(1024), dim3(256), 0, stream>>>(
        Wih, Whh, bih, bhh, wih_bf, whh_bf, biasc, scb, done);
    lstm_main<<<dim3(NBLK), dim3(256), 0, stream>>>(
        x, wih_bf, whh_bf, biasc, scb, cbuf, out, done);
}

// Round 3
// 17368.816 us; speedup vs baseline: 1.7410x; 1.1241x over previous
//
#include <hip/hip_runtime.h>

#define SEQ    1000
#define BATCH  256
#define HID    256
#define NL     10
#define G4H    1024                    // 4*HID
#define WELT   (NL * G4H * HID)        // 2,621,440 elements per weight tensor
#define BH     (BATCH * HID)           // 65,536
#define NBLK   160

typedef __bf16 bf16x8 __attribute__((ext_vector_type(8)));
typedef float  f32x4  __attribute__((ext_vector_type(4)));

// ---- ws layout (bytes) ----
// 0          : wih_bf   (5,242,880)
// 5,242,880  : whh_bf   (5,242,880)
// 10,485,760 : biasc    (40,960)      fp32, b_ih+b_hh combined
// 10,526,720 : scb      (2,621,440)   bf16 h-state, [NL][2(parity)][B][H]
// 13,148,160 : cbuf     (2,359,296)   bf16 layer handoff, [NL-1][2(parity)][B][H]
// 15,507,456 : done     (2,560)       per-(layer,btile) step counters, stride 16 uints

// -------- prologue --------
__global__ __launch_bounds__(256) void lstm_prep(
    const float* __restrict__ Wih, const float* __restrict__ Whh,
    const float* __restrict__ bih, const float* __restrict__ bhh,
    __bf16* __restrict__ wih_bf, __bf16* __restrict__ whh_bf,
    float* __restrict__ biasc, __bf16* __restrict__ scb,
    unsigned int* __restrict__ done)
{
    const int i0 = blockIdx.x * blockDim.x + threadIdx.x;
    const int stride = gridDim.x * blockDim.x;
    for (int i = i0; i < WELT; i += stride) {
        wih_bf[i] = (__bf16)Wih[i];
        whh_bf[i] = (__bf16)Whh[i];
    }
    for (int i = i0; i < NL * G4H; i += stride) biasc[i] = bih[i] + bhh[i];
    for (int i = i0; i < NL * 2 * BH; i += stride) scb[i] = (__bf16)0.0f;
    if (i0 < NL * 4 * 16) done[i0] = 0u;
}

// -------- relaxed spin (NO acquire -> no L2 invalidate). All lanes poll same addr. --------
__device__ __forceinline__ void spin_ge(const unsigned int* p, unsigned int tgt)
{
    while (__hip_atomic_load(p, __ATOMIC_RELAXED, __HIP_MEMORY_SCOPE_AGENT) < tgt)
        __builtin_amdgcn_s_sleep(4);
}

// -------- coherent 16B load: bypass L1+L2, read coherence point (L3) --------
__device__ __forceinline__ void ldg_coh(bf16x8& d, const __bf16* p)
{
    asm volatile("global_load_dwordx4 %0, %1, off sc0 sc1" : "=v"(d) : "v"(p));
}
__device__ __forceinline__ void wait_vm0()
{
    asm volatile("s_waitcnt vmcnt(0)" ::: "memory");
}

// -------- main persistent kernel --------
// Mapping (blk%8 = XCD assumed, perf-only):
//   blk < 128 : j = blk&7 (layer j on XCD j), tile = blk>>3
//   blk >=128 : j = 8+((blk&7)>>2), bt = blk&3, ht = (blk-128)>>3, tile = bt<<2|ht
//               -> each (j,bt) group of 4 blocks shares one XCD
// tile: b0=(tile>>2)*64, h0=(tile&3)*64. Wave v owns h cols h0+v*16..+16.
__global__ __launch_bounds__(256, 1) void lstm_main(
    const float* __restrict__ x,
    const __bf16* __restrict__ wih_bf, const __bf16* __restrict__ whh_bf,
    const float* __restrict__ biasc,
    __bf16* __restrict__ scb, __bf16* __restrict__ cbuf,
    float* __restrict__ out, unsigned int* __restrict__ done)
{
    __shared__ __bf16 Alds[64][512];   // 64 KiB; 16B-chunk XOR swizzle

    const int blk  = blockIdx.x;
    int j, tile;
    if (blk < 128) { j = blk & 7; tile = blk >> 3; }
    else           { j = 8 + ((blk & 7) >> 2); tile = ((blk & 3) << 2) | ((blk - 128) >> 3); }
    const int bt   = tile >> 2;
    const int b0   = bt << 6;
    const int h0   = (tile & 3) << 6;
    const int tid  = threadIdx.x;
    const int v    = tid >> 6;
    const int lane = tid & 63;
    const int m    = lane & 15;        // MFMA A-row / B-col / D-col index
    const int q    = lane >> 4;        // quad
    const int hw   = h0 + v * 16 + m;  // this lane's h column (N index)

    unsigned int* done_self = done + (j * 4 + bt) * 16;
    unsigned int* done_prod = done + ((j - 1) * 4 + bt) * 16;
    unsigned int* done_cons = done + ((j + 1) * 4 + bt) * 16;

    const __bf16* bihp[4];
    float biasg[4];
    bf16x8 wfhh[8][4];                 // Whh fragments resident in registers (128 VGPRs)
#pragma unroll
    for (int g = 0; g < 4; ++g) {
        const size_t row = (size_t)j * G4H + g * HID + hw;
        bihp[g] = wih_bf + row * HID + q * 8;
        biasg[g] = biasc[(size_t)j * G4H + g * HID + hw];
        const __bf16* hh = whh_bf + row * HID + q * 8;
#pragma unroll
        for (int ch = 0; ch < 8; ++ch)
            wfhh[ch][g] = *(const bf16x8*)(hh + ch * 32);
    }

    float c_state[4][4];
#pragma unroll
    for (int bs = 0; bs < 4; ++bs)
#pragma unroll
        for (int r = 0; r < 4; ++r) c_state[bs][r] = 0.0f;

    for (int t = 0; t < SEQ; ++t) {
        const int par = t & 1;
        const __bf16* hprev = scb + (size_t)(j * 2 + ((t + 1) & 1)) * BH;
        __bf16* hout = scb + (size_t)(j * 2 + par) * BH;

        // ---- W2: own group finished step t-1 (h ready, slots reusable) ----
        if (t >= 1) spin_ge(done_self, 4u * (unsigned)t);

        // ---- stage h_prev into Alds hi half (chunks 32..63), coherent loads ----
        {
            bf16x8 tmp[8];
#pragma unroll
            for (int i = 0; i < 8; ++i) {
                const int row = i * 8 + v * 2 + (lane >> 5);
                const int c32 = lane & 31;
                ldg_coh(tmp[i], hprev + (size_t)(b0 + row) * HID + c32 * 8);
            }
            wait_vm0();
#pragma unroll
            for (int i = 0; i < 8; ++i) {
                const int row = i * 8 + v * 2 + (lane >> 5);
                const int c32 = lane & 31;
                const int cp  = (32 + c32) ^ (row & 7);
                *(bf16x8*)&Alds[0][(size_t)row * 512 + cp * 8] = tmp[i];
            }
        }
        __syncthreads();   // B1

        // ---- acc = bias; Whh @ h_prev from register-resident fragments ----
        f32x4 acc[4][4];   // [b-subtile][gate]
#pragma unroll
        for (int g = 0; g < 4; ++g) {
            const float bb = biasg[g];
            const f32x4 bv = {bb, bb, bb, bb};
#pragma unroll
            for (int bs = 0; bs < 4; ++bs) acc[bs][g] = bv;
        }
#pragma unroll
        for (int ch = 0; ch < 8; ++ch) {
#pragma unroll
            for (int bs = 0; bs < 4; ++bs) {
                const int rowA = bs * 16 + m;
                const int cp = (32 + ch * 4 + q) ^ (rowA & 7);
                const bf16x8 af = *(const bf16x8*)&Alds[rowA][cp * 8];
#pragma unroll
                for (int g = 0; g < 4; ++g)
                    acc[bs][g] = __builtin_amdgcn_mfma_f32_16x16x32_bf16(
                        af, wfhh[ch][g], acc[bs][g], 0, 0, 0);
            }
        }

        // ---- W1: producer finished step t; W3: consumer finished t-2 ----
        if (j > 0) spin_ge(done_prod, 4u * (unsigned)(t + 1));
        if (j < NL - 1 && t >= 2) spin_ge(done_cons, 4u * (unsigned)(t - 1));

        // ---- stage cur into Alds lo half (chunks 0..31) ----
        if (j == 0) {
            const float* xt = x + (size_t)t * BH;
#pragma unroll
            for (int i = 0; i < 8; ++i) {
                const int row = i * 8 + v * 2 + (lane >> 5);
                const int c32 = lane & 31;
                const int cp  = c32 ^ (row & 7);
                const float4* p = (const float4*)(xt + (size_t)(b0 + row) * HID + c32 * 8);
                const float4 u0 = p[0];
                const float4 u1 = p[1];
                bf16x8 vv;
                vv[0] = (__bf16)u0.x; vv[1] = (__bf16)u0.y;
                vv[2] = (__bf16)u0.z; vv[3] = (__bf16)u0.w;
                vv[4] = (__bf16)u1.x; vv[5] = (__bf16)u1.y;
                vv[6] = (__bf16)u1.z; vv[7] = (__bf16)u1.w;
                *(bf16x8*)&Alds[0][(size_t)row * 512 + cp * 8] = vv;
            }
        } else {
            const __bf16* ct = cbuf + (size_t)((j - 1) * 2 + par) * BH;
            bf16x8 tmp[8];
#pragma unroll
            for (int i = 0; i < 8; ++i) {
                const int row = i * 8 + v * 2 + (lane >> 5);
                const int c32 = lane & 31;
                ldg_coh(tmp[i], ct + (size_t)(b0 + row) * HID + c32 * 8);
            }
            wait_vm0();
#pragma unroll
            for (int i = 0; i < 8; ++i) {
                const int row = i * 8 + v * 2 + (lane >> 5);
                const int c32 = lane & 31;
                const int cp  = c32 ^ (row & 7);
                *(bf16x8*)&Alds[0][(size_t)row * 512 + cp * 8] = tmp[i];
            }
        }
        __syncthreads();   // B2

        // ---- Wih @ cur (streamed from L2 — stays resident now, no invalidates) ----
#pragma unroll
        for (int ch = 0; ch < 8; ++ch) {
            bf16x8 bfr[4];
#pragma unroll
            for (int g = 0; g < 4; ++g)
                bfr[g] = *(const bf16x8*)(bihp[g] + ch * 32);
#pragma unroll
            for (int bs = 0; bs < 4; ++bs) {
                const int rowA = bs * 16 + m;
                const int cp = (ch * 4 + q) ^ (rowA & 7);
                const bf16x8 af = *(const bf16x8*)&Alds[rowA][cp * 8];
#pragma unroll
                for (int g = 0; g < 4; ++g)
                    acc[bs][g] = __builtin_amdgcn_mfma_f32_16x16x32_bf16(
                        af, bfr[g], acc[bs][g], 0, 0, 0);
            }
        }

        // ---- epilogue: activations, state update, publish ----
        __bf16* cnext = (j < NL - 1) ? (cbuf + (size_t)(j * 2 + par) * BH) : (__bf16*)0;
#pragma unroll
        for (int bs = 0; bs < 4; ++bs) {
#pragma unroll
            for (int r = 0; r < 4; ++r) {
                const int b = b0 + bs * 16 + q * 4 + r;
                const float gi = acc[bs][0][r];
                const float gf = acc[bs][1][r];
                const float gg = acc[bs][2][r];
                const float go = acc[bs][3][r];
                const float ii = 1.0f / (1.0f + __expf(-gi));
                const float ff = 1.0f / (1.0f + __expf(-gf));
                const float tg = 1.0f - 2.0f / (__expf(2.0f * gg) + 1.0f);
                const float oo = 1.0f / (1.0f + __expf(-go));
                const float cn = ff * c_state[bs][r] + ii * tg;   // c' (next layer's input)
                const float tc = 1.0f - 2.0f / (__expf(2.0f * cn) + 1.0f);
                const float hn = oo * tc;                          // h' (recurrent operand)
                c_state[bs][r] = cn;
                hout[(size_t)b * HID + hw] = (__bf16)hn;
                if (j < NL - 1) {
                    cnext[(size_t)b * HID + hw] = (__bf16)cn;
                } else if (t == SEQ - 1) {
                    out[(size_t)b * HID + hw] = cn;                // fp32, unquantized
                }
            }
        }

        __syncthreads();   // B3: all waves' stores drained to L2 before publish
        if (tid == 0)
            __hip_atomic_fetch_add(done_self, 1u, __ATOMIC_RELEASE,
                                   __HIP_MEMORY_SCOPE_AGENT);   // buffer_wbl2 -> L3, then inc
    }
}

extern "C" void kernel_launch(void* const* d_in, const int* in_sizes, int n_in,
                              void* d_out, int out_size, void* d_ws, size_t ws_size,
                              hipStream_t stream)
{
    (void)in_sizes; (void)n_in; (void)out_size; (void)ws_size;
    const float* x   = (const float*)d_in[0];
    const float* Wih = (const float*)d_in[1];
    const float* Whh = (const float*)d_in[2];
    const float* bih = (const float*)d_in[3];
    const float* bhh = (const float*)d_in[4];
    float* out = (float*)d_out;

    char* ws = (char*)d_ws;
    __bf16* wih_bf = (__bf16*)(ws);
    __bf16* whh_bf = (__bf16*)(ws + 5242880);
    float*  biasc  = (float*) (ws + 10485760);
    __bf16* scb    = (__bf16*)(ws + 10526720);
    __bf16* cbuf   = (__bf16*)(ws + 13148160);
    unsigned int* done = (unsigned int*)(ws + 15507456);

    lstm_prep<<<dim3(1024), dim3(256), 0, stream>>>(
        Wih, Whh, bih, bhh, wih_bf, whh_bf, biasc, scb, done);
    lstm_main<<<dim3(NBLK), dim3(256), 0, stream>>>(
        x, wih_bf, whh_bf, biasc, scb, cbuf, out, done);
}

// Round 4
// 14176.736 us; speedup vs baseline: 2.1330x; 1.2252x over previous
//
#include <hip/hip_runtime.h>

#define SEQ    1000
#define BATCH  256
#define HID    256
#define NL     10
#define G4H    1024                    // 4*HID
#define WELT   (NL * G4H * HID)        // 2,621,440 elements per weight tensor
#define BH     (BATCH * HID)           // 65,536
#define NBLK   160
#define DSTR   32                      // done-flag stride in uints (128 B, no false sharing)

typedef __bf16 bf16x8 __attribute__((ext_vector_type(8)));
typedef float  f32x4  __attribute__((ext_vector_type(4)));

// ---- ws layout (bytes) ----
// 0          : wih_bf   (5,242,880)
// 5,242,880  : whh_bf   (5,242,880)
// 10,485,760 : biasc    (40,960)      fp32, b_ih+b_hh combined
// 10,526,720 : scb      (2,621,440)   bf16 h-state, [NL][2(parity)][B][H]
// 13,148,160 : cbuf     (2,359,296)   bf16 layer handoff, [NL-1][2(parity)][B][H]
// 15,507,456 : done     (5,120)       per-(layer,btile) step counters, stride DSTR uints

// -------- prologue --------
__global__ __launch_bounds__(256) void lstm_prep(
    const float* __restrict__ Wih, const float* __restrict__ Whh,
    const float* __restrict__ bih, const float* __restrict__ bhh,
    __bf16* __restrict__ wih_bf, __bf16* __restrict__ whh_bf,
    float* __restrict__ biasc, __bf16* __restrict__ scb,
    unsigned int* __restrict__ done)
{
    const int i0 = blockIdx.x * blockDim.x + threadIdx.x;
    const int stride = gridDim.x * blockDim.x;
    for (int i = i0; i < WELT; i += stride) {
        wih_bf[i] = (__bf16)Wih[i];
        whh_bf[i] = (__bf16)Whh[i];
    }
    for (int i = i0; i < NL * G4H; i += stride) biasc[i] = bih[i] + bhh[i];
    for (int i = i0; i < NL * 2 * BH; i += stride) scb[i] = (__bf16)0.0f;
    if (i0 < NL * 4 * DSTR) done[i0] = 0u;
}

// -------- relaxed spin: NO acquire, NO cache maintenance. Atomic load reads coherence pt. --------
__device__ __forceinline__ void spin_ge(const unsigned int* p, unsigned int tgt)
{
    while (__hip_atomic_load(p, __ATOMIC_RELAXED, __HIP_MEMORY_SCOPE_AGENT) < tgt)
        __builtin_amdgcn_s_sleep(4);
}

// -------- coherent 16B load: bypass L1+L2, read coherence point (cross-XCD data) --------
__device__ __forceinline__ void ldg_coh(bf16x8& d, const __bf16* p)
{
    asm volatile("global_load_dwordx4 %0, %1, off sc0 sc1" : "=v"(d) : "v"(p));
}
// -------- L2-coherent 16B load: bypass L1 only (intra-XCD data, hits local L2) --------
__device__ __forceinline__ void ldg_l2(bf16x8& d, const __bf16* p)
{
    asm volatile("global_load_dwordx4 %0, %1, off sc0" : "=v"(d) : "v"(p));
}
// -------- coherent 2B store: write-through to coherence point (no L2 dirty line) --------
__device__ __forceinline__ void stg_coh_b16(__bf16* p, __bf16 v)
{
    asm volatile("global_store_short %0, %1, off sc0 sc1" :: "v"(p), "v"(v) : "memory");
}
__device__ __forceinline__ void wait_vm0()
{
    asm volatile("s_waitcnt vmcnt(0)" ::: "memory");
}

// -------- main persistent kernel --------
// Mapping (blk%8 = XCD assumed, perf-only):
//   blk < 128 : j = blk&7 (layer j on XCD j), tile = blk>>3
//   blk >=128 : j = 8+((blk&7)>>2), tile = ((blk&3)<<2)|((blk-128)>>3)
// Groups of 4 blocks sharing (j, b-tile) are co-located on one XCD -> h-exchange intra-XCD.
// tile: b0=(tile>>2)*64, h0=(tile&3)*64. Wave v owns h cols h0+v*16..+16.
__global__ __launch_bounds__(256, 1) void lstm_main(
    const float* __restrict__ x,
    const __bf16* __restrict__ wih_bf, const __bf16* __restrict__ whh_bf,
    const float* __restrict__ biasc,
    __bf16* __restrict__ scb, __bf16* __restrict__ cbuf,
    float* __restrict__ out, unsigned int* __restrict__ done)
{
    __shared__ __bf16 Alds[64][512];   // 64 KiB; 16B-chunk XOR swizzle

    const int blk  = blockIdx.x;
    int j, tile;
    if (blk < 128) { j = blk & 7; tile = blk >> 3; }
    else           { j = 8 + ((blk & 7) >> 2); tile = ((blk & 3) << 2) | ((blk - 128) >> 3); }
    const int bt   = tile >> 2;
    const int b0   = bt << 6;
    const int h0   = (tile & 3) << 6;
    const int tid  = threadIdx.x;
    const int v    = tid >> 6;
    const int lane = tid & 63;
    const int m    = lane & 15;        // MFMA A-row / B-col / D-col index
    const int q    = lane >> 4;        // quad
    const int hw   = h0 + v * 16 + m;  // this lane's h column (N index)

    unsigned int* done_self = done + (j * 4 + bt) * DSTR;
    unsigned int* done_prod = done + ((j - 1) * 4 + bt) * DSTR;
    unsigned int* done_cons = done + ((j + 1) * 4 + bt) * DSTR;

    const __bf16* bihp[4];
    float biasg[4];
    bf16x8 wfhh[8][4];                 // Whh fragments resident in registers (128 VGPRs)
#pragma unroll
    for (int g = 0; g < 4; ++g) {
        const size_t row = (size_t)j * G4H + g * HID + hw;
        bihp[g] = wih_bf + row * HID + q * 8;
        biasg[g] = biasc[(size_t)j * G4H + g * HID + hw];
        const __bf16* hh = whh_bf + row * HID + q * 8;
#pragma unroll
        for (int ch = 0; ch < 8; ++ch)
            wfhh[ch][g] = *(const bf16x8*)(hh + ch * 32);
    }

    float c_state[4][4];
#pragma unroll
    for (int bs = 0; bs < 4; ++bs)
#pragma unroll
        for (int r = 0; r < 4; ++r) c_state[bs][r] = 0.0f;

    for (int t = 0; t < SEQ; ++t) {
        const int par = t & 1;
        const __bf16* hprev = scb + (size_t)(j * 2 + ((t + 1) & 1)) * BH;
        __bf16* hout = scb + (size_t)(j * 2 + par) * BH;

        // ---- W2: own group finished step t-1 (h ready, slots reusable) ----
        if (t >= 1) spin_ge(done_self, 4u * (unsigned)t);

        // ---- stage h_prev into Alds hi half (chunks 32..63); intra-XCD -> L1-bypass only ----
        {
            bf16x8 tmp[8];
#pragma unroll
            for (int i = 0; i < 8; ++i) {
                const int row = i * 8 + v * 2 + (lane >> 5);
                const int c32 = lane & 31;
                ldg_l2(tmp[i], hprev + (size_t)(b0 + row) * HID + c32 * 8);
            }
            wait_vm0();
#pragma unroll
            for (int i = 0; i < 8; ++i) {
                const int row = i * 8 + v * 2 + (lane >> 5);
                const int c32 = lane & 31;
                const int cp  = (32 + c32) ^ (row & 7);
                *(bf16x8*)&Alds[0][(size_t)row * 512 + cp * 8] = tmp[i];
            }
        }
        __syncthreads();   // B1

        // ---- acc = bias; Whh @ h_prev from register-resident fragments ----
        f32x4 acc[4][4];   // [b-subtile][gate]
#pragma unroll
        for (int g = 0; g < 4; ++g) {
            const float bb = biasg[g];
            const f32x4 bv = {bb, bb, bb, bb};
#pragma unroll
            for (int bs = 0; bs < 4; ++bs) acc[bs][g] = bv;
        }
#pragma unroll
        for (int ch = 0; ch < 8; ++ch) {
#pragma unroll
            for (int bs = 0; bs < 4; ++bs) {
                const int rowA = bs * 16 + m;
                const int cp = (32 + ch * 4 + q) ^ (rowA & 7);
                const bf16x8 af = *(const bf16x8*)&Alds[rowA][cp * 8];
#pragma unroll
                for (int g = 0; g < 4; ++g)
                    acc[bs][g] = __builtin_amdgcn_mfma_f32_16x16x32_bf16(
                        af, wfhh[ch][g], acc[bs][g], 0, 0, 0);
            }
        }

        // ---- W1: producer finished step t; W3: consumer finished t-2 ----
        if (j > 0) spin_ge(done_prod, 4u * (unsigned)(t + 1));
        if (j < NL - 1 && t >= 2) spin_ge(done_cons, 4u * (unsigned)(t - 1));

        // ---- stage cur into Alds lo half (chunks 0..31) ----
        if (j == 0) {
            const float* xt = x + (size_t)t * BH;
#pragma unroll
            for (int i = 0; i < 8; ++i) {
                const int row = i * 8 + v * 2 + (lane >> 5);
                const int c32 = lane & 31;
                const int cp  = c32 ^ (row & 7);
                const float4* p = (const float4*)(xt + (size_t)(b0 + row) * HID + c32 * 8);
                const float4 u0 = p[0];
                const float4 u1 = p[1];
                bf16x8 vv;
                vv[0] = (__bf16)u0.x; vv[1] = (__bf16)u0.y;
                vv[2] = (__bf16)u0.z; vv[3] = (__bf16)u0.w;
                vv[4] = (__bf16)u1.x; vv[5] = (__bf16)u1.y;
                vv[6] = (__bf16)u1.z; vv[7] = (__bf16)u1.w;
                *(bf16x8*)&Alds[0][(size_t)row * 512 + cp * 8] = vv;
            }
        } else {
            const __bf16* ct = cbuf + (size_t)((j - 1) * 2 + par) * BH;
            bf16x8 tmp[8];
#pragma unroll
            for (int i = 0; i < 8; ++i) {
                const int row = i * 8 + v * 2 + (lane >> 5);
                const int c32 = lane & 31;
                ldg_coh(tmp[i], ct + (size_t)(b0 + row) * HID + c32 * 8);  // cross-XCD
            }
            wait_vm0();
#pragma unroll
            for (int i = 0; i < 8; ++i) {
                const int row = i * 8 + v * 2 + (lane >> 5);
                const int c32 = lane & 31;
                const int cp  = c32 ^ (row & 7);
                *(bf16x8*)&Alds[0][(size_t)row * 512 + cp * 8] = tmp[i];
            }
        }
        __syncthreads();   // B2

        // ---- Wih @ cur (streamed from local L2 — never invalidated now) ----
#pragma unroll
        for (int ch = 0; ch < 8; ++ch) {
            bf16x8 bfr[4];
#pragma unroll
            for (int g = 0; g < 4; ++g)
                bfr[g] = *(const bf16x8*)(bihp[g] + ch * 32);
#pragma unroll
            for (int bs = 0; bs < 4; ++bs) {
                const int rowA = bs * 16 + m;
                const int cp = (ch * 4 + q) ^ (rowA & 7);
                const bf16x8 af = *(const bf16x8*)&Alds[rowA][cp * 8];
#pragma unroll
                for (int g = 0; g < 4; ++g)
                    acc[bs][g] = __builtin_amdgcn_mfma_f32_16x16x32_bf16(
                        af, bfr[g], acc[bs][g], 0, 0, 0);
            }
        }

        // ---- epilogue: activations, state update, publish ----
        __bf16* cnext = (j < NL - 1) ? (cbuf + (size_t)(j * 2 + par) * BH) : (__bf16*)0;
#pragma unroll
        for (int bs = 0; bs < 4; ++bs) {
#pragma unroll
            for (int r = 0; r < 4; ++r) {
                const int b = b0 + bs * 16 + q * 4 + r;
                const float gi = acc[bs][0][r];
                const float gf = acc[bs][1][r];
                const float gg = acc[bs][2][r];
                const float go = acc[bs][3][r];
                const float ii = 1.0f / (1.0f + __expf(-gi));
                const float ff = 1.0f / (1.0f + __expf(-gf));
                const float tg = 1.0f - 2.0f / (__expf(2.0f * gg) + 1.0f);
                const float oo = 1.0f / (1.0f + __expf(-go));
                const float cn = ff * c_state[bs][r] + ii * tg;   // c' (next layer's input)
                const float tc = 1.0f - 2.0f / (__expf(2.0f * cn) + 1.0f);
                const float hn = oo * tc;                          // h' (recurrent operand)
                c_state[bs][r] = cn;
                hout[(size_t)b * HID + hw] = (__bf16)hn;           // intra-XCD: normal store -> L2
                if (j < NL - 1) {
                    stg_coh_b16(cnext + (size_t)b * HID + hw, (__bf16)cn);  // cross-XCD: WT to L3
                } else if (t == SEQ - 1) {
                    out[(size_t)b * HID + hw] = cn;                // fp32; kernel-end release covers
                }
            }
        }

        wait_vm0();        // all this wave's h/c stores acknowledged at their coherence level
        __syncthreads();   // B3: every wave's stores done before the flag bump
        if (tid == 0)
            __hip_atomic_fetch_add(done_self, 1u, __ATOMIC_RELAXED,
                                   __HIP_MEMORY_SCOPE_AGENT);   // no fence, no wbl2
    }
}

extern "C" void kernel_launch(void* const* d_in, const int* in_sizes, int n_in,
                              void* d_out, int out_size, void* d_ws, size_t ws_size,
                              hipStream_t stream)
{
    (void)in_sizes; (void)n_in; (void)out_size; (void)ws_size;
    const float* x   = (const float*)d_in[0];
    const float* Wih = (const float*)d_in[1];
    const float* Whh = (const float*)d_in[2];
    const float* bih = (const float*)d_in[3];
    const float* bhh = (const float*)d_in[4];
    float* out = (float*)d_out;

    char* ws = (char*)d_ws;
    __bf16* wih_bf = (__bf16*)(ws);
    __bf16* whh_bf = (__bf16*)(ws + 5242880);
    float*  biasc  = (float*) (ws + 10485760);
    __bf16* scb    = (__bf16*)(ws + 10526720);
    __bf16* cbuf   = (__bf16*)(ws + 13148160);
    unsigned int* done = (unsigned int*)(ws + 15507456);

    lstm_prep<<<dim3(1024), dim3(256), 0, stream>>>(
        Wih, Whh, bih, bhh, wih_bf, whh_bf, biasc, scb, done);
    lstm_main<<<dim3(NBLK), dim3(256), 0, stream>>>(
        x, wih_bf, whh_bf, biasc, scb, cbuf, out, done);
}